// Round 1
// baseline (235.435 us; speedup 1.0000x reference)
//
#include <hip/hip_runtime.h>

#define NTHREADS 256

// YOLO-style loss: per-cell 12-channel pred/target, reduce to 5 components.
__global__ __launch_bounds__(NTHREADS) void yolo_loss_kernel(
    const float4* __restrict__ pred, const float4* __restrict__ targ,
    float* __restrict__ acc, int ncells)
{
    float loc = 0.f, contain = 0.f, notcont = 0.f, nooobj = 0.f, cls = 0.f;

    int tid = blockIdx.x * NTHREADS + threadIdx.x;
    int stride = gridDim.x * NTHREADS;

    for (int c = tid; c < ncells; c += stride) {
        // 12 floats per cell = 3 x float4, base always 16B-aligned (48B cell stride)
        float4 pa = pred[3 * c + 0];
        float4 pb = pred[3 * c + 1];
        float4 pc = pred[3 * c + 2];
        float4 ta = targ[3 * c + 0];
        float4 tb = targ[3 * c + 1];
        float4 tc = targ[3 * c + 2];

        float p0 = pa.x, p1 = pa.y, p2 = pa.z, p3 = pa.w;
        float p4 = pb.x, p5 = pb.y, p6 = pb.z, p7 = pb.w;
        float p8 = pc.x, p9 = pc.y, p10 = pc.z, p11 = pc.w;
        float t0 = ta.x, t1 = ta.y, t2 = ta.z, t3 = ta.w;
        float t4 = tb.x, t5 = tb.y, t6 = tb.z, t7 = tb.w;
        float t8 = tc.x, t9 = tc.y, t10 = tc.z, t11 = tc.w;

        float coo = (t4 > 0.5f) ? 1.f : 0.f;
        float noo = 1.f - coo;

        // --- no-object conf loss (channels 4, 9); relu(p - 0.5 + 0.3) = relu(p - 0.2)
        float d0 = fmaxf(p4 - 0.2f, 0.f) - t4;
        float d1 = fmaxf(p9 - 0.2f, 0.f) - t9;
        nooobj += noo * (d0 * d0 + d1 * d1);

        // --- IoU of both pred boxes vs FIRST target box (t0..t3)
        float tx0 = t0 - 0.5f * t2, ty0 = t1 - 0.5f * t3;
        float tx1 = t0 + 0.5f * t2, ty1 = t1 + 0.5f * t3;
        float a2 = t2 * t3;

        // pred box A = p0..p3 (cx,cy,w,h)
        float ax0 = p0 - 0.5f * p2, ay0 = p1 - 0.5f * p3;
        float ax1 = p0 + 0.5f * p2, ay1 = p1 + 0.5f * p3;
        float iwA = fmaxf(fminf(ax1, tx1) - fmaxf(ax0, tx0), 0.f);
        float ihA = fmaxf(fminf(ay1, ty1) - fmaxf(ay0, ty0), 0.f);
        float interA = iwA * ihA;
        float iouA = interA / (p2 * p3 + a2 - interA);

        // pred box B = p5..p8 (cx,cy,w,h)
        float bx0 = p5 - 0.5f * p7, by0 = p6 - 0.5f * p8;
        float bx1 = p5 + 0.5f * p7, by1 = p6 + 0.5f * p8;
        float iwB = fmaxf(fminf(bx1, tx1) - fmaxf(bx0, tx0), 0.f);
        float ihB = fmaxf(fminf(by1, ty1) - fmaxf(by0, ty0), 0.f);
        float interB = iwB * ihB;
        float iouB = interB / (p7 * p8 + a2 - interB);

        // argmax: ties -> index 0, so strict greater-than selects box 1
        bool sel = iouB > iouA;

        float pr0 = sel ? p5 : p0, pr1 = sel ? p6 : p1;
        float pr2 = sel ? p7 : p2, pr3 = sel ? p8 : p3;
        float pr4 = sel ? p9 : p4;
        float tr0 = sel ? t5 : t0, tr1 = sel ? t6 : t1;
        float tr2 = sel ? t7 : t2, tr3 = sel ? t8 : t3;
        float tr4 = sel ? t9 : t4;
        float pn4 = sel ? p4 : p9;   // the NOT-responsible pred conf

        float dc = pr4 - tr4;
        contain += coo * dc * dc;

        float dx = pr0 - tr0, dy = pr1 - tr1;
        float dw = sqrtf(pr2) - sqrtf(tr2);
        float dh = sqrtf(pr3) - sqrtf(tr3);
        loc += coo * (dx * dx + dy * dy + dw * dw + dh * dh);

        notcont += coo * pn4 * pn4;

        float c0 = p10 - t10, c1 = p11 - t11;
        cls += coo * (c0 * c0 + c1 * c1);
    }

    // --- wave64 butterfly-free down-reduce
    #pragma unroll
    for (int off = 32; off > 0; off >>= 1) {
        loc     += __shfl_down(loc, off, 64);
        contain += __shfl_down(contain, off, 64);
        notcont += __shfl_down(notcont, off, 64);
        nooobj  += __shfl_down(nooobj, off, 64);
        cls     += __shfl_down(cls, off, 64);
    }

    __shared__ float sm[NTHREADS / 64][5];
    int wave = threadIdx.x >> 6;
    int lane = threadIdx.x & 63;
    if (lane == 0) {
        sm[wave][0] = loc; sm[wave][1] = contain; sm[wave][2] = notcont;
        sm[wave][3] = nooobj; sm[wave][4] = cls;
    }
    __syncthreads();
    if (threadIdx.x == 0) {
        float s0 = 0.f, s1 = 0.f, s2 = 0.f, s3 = 0.f, s4 = 0.f;
        #pragma unroll
        for (int w = 0; w < NTHREADS / 64; ++w) {
            s0 += sm[w][0]; s1 += sm[w][1]; s2 += sm[w][2];
            s3 += sm[w][3]; s4 += sm[w][4];
        }
        atomicAdd(&acc[0], s0);
        atomicAdd(&acc[1], s1);
        atomicAdd(&acc[2], s2);
        atomicAdd(&acc[3], s3);
        atomicAdd(&acc[4], s4);
    }
}

__global__ void finalize_kernel(const float* __restrict__ acc, float* __restrict__ out)
{
    float part0 = 1.4f * acc[0];   // LOC_SCALE * loc
    float part1 = 4.0f * acc[1];   // CONTAIN_SCALE * contain
    float part2 = acc[2];          // not_contain
    float part3 = 1.2f * acc[3];   // L_NOOBJ * nooobj
    float part4 = 0.5f * acc[4];   // CLASS_SCALE * class
    out[0] = part0 + part1 + part2 + part3 + part4;
    out[1] = part0;
    out[2] = part1;
    out[3] = part2;
    out[4] = part3;
    out[5] = part4;
}

extern "C" void kernel_launch(void* const* d_in, const int* in_sizes, int n_in,
                              void* d_out, int out_size, void* d_ws, size_t ws_size,
                              hipStream_t stream)
{
    const float4* pred = (const float4*)d_in[0];
    const float4* targ = (const float4*)d_in[1];
    float* acc = (float*)d_ws;
    float* out = (float*)d_out;
    int ncells = in_sizes[0] / 12;   // 64*128*128 = 1,048,576

    // d_ws is re-poisoned to 0xAA before every timed launch — zero it each call.
    hipMemsetAsync(acc, 0, 5 * sizeof(float), stream);

    // 2048 blocks x 256 threads -> 2 cells per thread, grid-stride.
    yolo_loss_kernel<<<2048, NTHREADS, 0, stream>>>(pred, targ, acc, ncells);
    finalize_kernel<<<1, 1, 0, stream>>>(acc, out);
}

// Round 2
// 118.878 us; speedup vs baseline: 1.9805x; 1.9805x over previous
//
#include <hip/hip_runtime.h>

#define NTHREADS 256
#define NBLOCKS 2048

// YOLO-style loss: per-cell 12-channel pred/target, reduce to 5 components.
// Stage 1: per-block partials into d_ws (no atomics — R0 showed 10K
// same-address atomicAdds serialized for ~120us).
__global__ __launch_bounds__(NTHREADS) void yolo_loss_kernel(
    const float4* __restrict__ pred, const float4* __restrict__ targ,
    float* __restrict__ partial, int ncells)
{
    float loc = 0.f, contain = 0.f, notcont = 0.f, nooobj = 0.f, cls = 0.f;

    int tid = blockIdx.x * NTHREADS + threadIdx.x;
    int stride = gridDim.x * NTHREADS;

    for (int c = tid; c < ncells; c += stride) {
        // 12 floats per cell = 3 x float4, base always 16B-aligned (48B cell stride)
        float4 pa = pred[3 * c + 0];
        float4 pb = pred[3 * c + 1];
        float4 pc = pred[3 * c + 2];
        float4 ta = targ[3 * c + 0];
        float4 tb = targ[3 * c + 1];
        float4 tc = targ[3 * c + 2];

        float p0 = pa.x, p1 = pa.y, p2 = pa.z, p3 = pa.w;
        float p4 = pb.x, p5 = pb.y, p6 = pb.z, p7 = pb.w;
        float p8 = pc.x, p9 = pc.y, p10 = pc.z, p11 = pc.w;
        float t0 = ta.x, t1 = ta.y, t2 = ta.z, t3 = ta.w;
        float t4 = tb.x, t5 = tb.y, t6 = tb.z, t7 = tb.w;
        float t8 = tc.x, t9 = tc.y, t10 = tc.z, t11 = tc.w;

        float coo = (t4 > 0.5f) ? 1.f : 0.f;
        float noo = 1.f - coo;

        // --- no-object conf loss (channels 4, 9); relu(p - 0.5 + 0.3) = relu(p - 0.2)
        float d0 = fmaxf(p4 - 0.2f, 0.f) - t4;
        float d1 = fmaxf(p9 - 0.2f, 0.f) - t9;
        nooobj += noo * (d0 * d0 + d1 * d1);

        // --- IoU of both pred boxes vs FIRST target box (t0..t3)
        float tx0 = t0 - 0.5f * t2, ty0 = t1 - 0.5f * t3;
        float tx1 = t0 + 0.5f * t2, ty1 = t1 + 0.5f * t3;
        float a2 = t2 * t3;

        // pred box A = p0..p3 (cx,cy,w,h)
        float ax0 = p0 - 0.5f * p2, ay0 = p1 - 0.5f * p3;
        float ax1 = p0 + 0.5f * p2, ay1 = p1 + 0.5f * p3;
        float iwA = fmaxf(fminf(ax1, tx1) - fmaxf(ax0, tx0), 0.f);
        float ihA = fmaxf(fminf(ay1, ty1) - fmaxf(ay0, ty0), 0.f);
        float interA = iwA * ihA;
        float iouA = interA / (p2 * p3 + a2 - interA);

        // pred box B = p5..p8 (cx,cy,w,h)
        float bx0 = p5 - 0.5f * p7, by0 = p6 - 0.5f * p8;
        float bx1 = p5 + 0.5f * p7, by1 = p6 + 0.5f * p8;
        float iwB = fmaxf(fminf(bx1, tx1) - fmaxf(bx0, tx0), 0.f);
        float ihB = fmaxf(fminf(by1, ty1) - fmaxf(by0, ty0), 0.f);
        float interB = iwB * ihB;
        float iouB = interB / (p7 * p8 + a2 - interB);

        // argmax: ties -> index 0, so strict greater-than selects box 1
        bool sel = iouB > iouA;

        float pr0 = sel ? p5 : p0, pr1 = sel ? p6 : p1;
        float pr2 = sel ? p7 : p2, pr3 = sel ? p8 : p3;
        float pr4 = sel ? p9 : p4;
        float tr0 = sel ? t5 : t0, tr1 = sel ? t6 : t1;
        float tr2 = sel ? t7 : t2, tr3 = sel ? t8 : t3;
        float tr4 = sel ? t9 : t4;
        float pn4 = sel ? p4 : p9;   // the NOT-responsible pred conf

        float dc = pr4 - tr4;
        contain += coo * dc * dc;

        float dx = pr0 - tr0, dy = pr1 - tr1;
        float dw = sqrtf(pr2) - sqrtf(tr2);
        float dh = sqrtf(pr3) - sqrtf(tr3);
        loc += coo * (dx * dx + dy * dy + dw * dw + dh * dh);

        notcont += coo * pn4 * pn4;

        float c0 = p10 - t10, c1 = p11 - t11;
        cls += coo * (c0 * c0 + c1 * c1);
    }

    // --- wave64 down-reduce
    #pragma unroll
    for (int off = 32; off > 0; off >>= 1) {
        loc     += __shfl_down(loc, off, 64);
        contain += __shfl_down(contain, off, 64);
        notcont += __shfl_down(notcont, off, 64);
        nooobj  += __shfl_down(nooobj, off, 64);
        cls     += __shfl_down(cls, off, 64);
    }

    __shared__ float sm[NTHREADS / 64][5];
    int wave = threadIdx.x >> 6;
    int lane = threadIdx.x & 63;
    if (lane == 0) {
        sm[wave][0] = loc; sm[wave][1] = contain; sm[wave][2] = notcont;
        sm[wave][3] = nooobj; sm[wave][4] = cls;
    }
    __syncthreads();
    if (threadIdx.x == 0) {
        float s0 = 0.f, s1 = 0.f, s2 = 0.f, s3 = 0.f, s4 = 0.f;
        #pragma unroll
        for (int w = 0; w < NTHREADS / 64; ++w) {
            s0 += sm[w][0]; s1 += sm[w][1]; s2 += sm[w][2];
            s3 += sm[w][3]; s4 += sm[w][4];
        }
        float* row = partial + (size_t)blockIdx.x * 8;   // 8-float padded slot
        row[0] = s0; row[1] = s1; row[2] = s2; row[3] = s3; row[4] = s4;
    }
}

// Stage 2: one block reduces the 2048 x 5 partials and applies scales.
__global__ __launch_bounds__(NTHREADS) void finalize_kernel(
    const float* __restrict__ partial, float* __restrict__ out)
{
    float s0 = 0.f, s1 = 0.f, s2 = 0.f, s3 = 0.f, s4 = 0.f;
    for (int b = threadIdx.x; b < NBLOCKS; b += NTHREADS) {
        const float* row = partial + (size_t)b * 8;
        s0 += row[0]; s1 += row[1]; s2 += row[2]; s3 += row[3]; s4 += row[4];
    }

    #pragma unroll
    for (int off = 32; off > 0; off >>= 1) {
        s0 += __shfl_down(s0, off, 64);
        s1 += __shfl_down(s1, off, 64);
        s2 += __shfl_down(s2, off, 64);
        s3 += __shfl_down(s3, off, 64);
        s4 += __shfl_down(s4, off, 64);
    }

    __shared__ float sm[NTHREADS / 64][5];
    int wave = threadIdx.x >> 6;
    int lane = threadIdx.x & 63;
    if (lane == 0) {
        sm[wave][0] = s0; sm[wave][1] = s1; sm[wave][2] = s2;
        sm[wave][3] = s3; sm[wave][4] = s4;
    }
    __syncthreads();
    if (threadIdx.x == 0) {
        float a0 = 0.f, a1 = 0.f, a2 = 0.f, a3 = 0.f, a4 = 0.f;
        #pragma unroll
        for (int w = 0; w < NTHREADS / 64; ++w) {
            a0 += sm[w][0]; a1 += sm[w][1]; a2 += sm[w][2];
            a3 += sm[w][3]; a4 += sm[w][4];
        }
        float part0 = 1.4f * a0;   // LOC_SCALE * loc
        float part1 = 4.0f * a1;   // CONTAIN_SCALE * contain
        float part2 = a2;          // not_contain
        float part3 = 1.2f * a3;   // L_NOOBJ * nooobj
        float part4 = 0.5f * a4;   // CLASS_SCALE * class
        out[0] = part0 + part1 + part2 + part3 + part4;
        out[1] = part0;
        out[2] = part1;
        out[3] = part2;
        out[4] = part3;
        out[5] = part4;
    }
}

extern "C" void kernel_launch(void* const* d_in, const int* in_sizes, int n_in,
                              void* d_out, int out_size, void* d_ws, size_t ws_size,
                              hipStream_t stream)
{
    const float4* pred = (const float4*)d_in[0];
    const float4* targ = (const float4*)d_in[1];
    float* partial = (float*)d_ws;     // NBLOCKS * 8 floats = 64 KB
    float* out = (float*)d_out;
    int ncells = in_sizes[0] / 12;     // 64*128*128 = 1,048,576

    // Every slot is overwritten each call — no zeroing needed, no atomics.
    yolo_loss_kernel<<<NBLOCKS, NTHREADS, 0, stream>>>(pred, targ, partial, ncells);
    finalize_kernel<<<1, NTHREADS, 0, stream>>>(partial, out);
}

// Round 3
// 116.848 us; speedup vs baseline: 2.0149x; 1.0174x over previous
//
#include <hip/hip_runtime.h>

#define NTHREADS 256
#define NBLOCKS 2048

// Per-cell loss contributions from 6 float4s (pred a,b,c / targ a,b,c).
__device__ __forceinline__ void cell_loss(
    float4 pa, float4 pb, float4 pc, float4 ta, float4 tb, float4 tc,
    float& loc, float& contain, float& notcont, float& nooobj, float& cls)
{
    float p0 = pa.x, p1 = pa.y, p2 = pa.z, p3 = pa.w;
    float p4 = pb.x, p5 = pb.y, p6 = pb.z, p7 = pb.w;
    float p8 = pc.x, p9 = pc.y, p10 = pc.z, p11 = pc.w;
    float t0 = ta.x, t1 = ta.y, t2 = ta.z, t3 = ta.w;
    float t4 = tb.x, t5 = tb.y, t6 = tb.z, t7 = tb.w;
    float t8 = tc.x, t9 = tc.y, t10 = tc.z, t11 = tc.w;

    float coo = (t4 > 0.5f) ? 1.f : 0.f;
    float noo = 1.f - coo;

    // no-object conf loss (channels 4, 9); relu(p - 0.5 + 0.3) = relu(p - 0.2)
    float d0 = fmaxf(p4 - 0.2f, 0.f) - t4;
    float d1 = fmaxf(p9 - 0.2f, 0.f) - t9;
    nooobj += noo * (d0 * d0 + d1 * d1);

    // IoU of both pred boxes vs FIRST target box (t0..t3)
    float tx0 = t0 - 0.5f * t2, ty0 = t1 - 0.5f * t3;
    float tx1 = t0 + 0.5f * t2, ty1 = t1 + 0.5f * t3;
    float a2 = t2 * t3;

    float ax0 = p0 - 0.5f * p2, ay0 = p1 - 0.5f * p3;
    float ax1 = p0 + 0.5f * p2, ay1 = p1 + 0.5f * p3;
    float iwA = fmaxf(fminf(ax1, tx1) - fmaxf(ax0, tx0), 0.f);
    float ihA = fmaxf(fminf(ay1, ty1) - fmaxf(ay0, ty0), 0.f);
    float interA = iwA * ihA;
    float iouA = interA / (p2 * p3 + a2 - interA);

    float bx0 = p5 - 0.5f * p7, by0 = p6 - 0.5f * p8;
    float bx1 = p5 + 0.5f * p7, by1 = p6 + 0.5f * p8;
    float iwB = fmaxf(fminf(bx1, tx1) - fmaxf(bx0, tx0), 0.f);
    float ihB = fmaxf(fminf(by1, ty1) - fmaxf(by0, ty0), 0.f);
    float interB = iwB * ihB;
    float iouB = interB / (p7 * p8 + a2 - interB);

    // argmax: ties -> index 0, so strict greater-than selects box 1
    bool sel = iouB > iouA;

    float pr0 = sel ? p5 : p0, pr1 = sel ? p6 : p1;
    float pr2 = sel ? p7 : p2, pr3 = sel ? p8 : p3;
    float pr4 = sel ? p9 : p4;
    float tr0 = sel ? t5 : t0, tr1 = sel ? t6 : t1;
    float tr2 = sel ? t7 : t2, tr3 = sel ? t8 : t3;
    float tr4 = sel ? t9 : t4;
    float pn4 = sel ? p4 : p9;

    float dc = pr4 - tr4;
    contain += coo * dc * dc;

    float dx = pr0 - tr0, dy = pr1 - tr1;
    float dw = sqrtf(pr2) - sqrtf(tr2);
    float dh = sqrtf(pr3) - sqrtf(tr3);
    loc += coo * (dx * dx + dy * dy + dw * dw + dh * dh);

    notcont += coo * pn4 * pn4;

    float c0 = p10 - t10, c1 = p11 - t11;
    cls += coo * (c0 * c0 + c1 * c1);
}

// Stage 1: each thread handles exactly 2 cells (tid, tid+stride), ALL 12
// float4 loads issued before compute for max memory-level parallelism.
__global__ __launch_bounds__(NTHREADS) void yolo_loss_kernel(
    const float4* __restrict__ pred, const float4* __restrict__ targ,
    float* __restrict__ partial, int ncells)
{
    int tid = blockIdx.x * NTHREADS + threadIdx.x;
    int stride = gridDim.x * NTHREADS;

    float loc = 0.f, contain = 0.f, notcont = 0.f, nooobj = 0.f, cls = 0.f;

    int c0 = tid;
    int c1 = tid + stride;
    bool h0 = c0 < ncells;
    bool h1 = c1 < ncells;
    int a0 = h0 ? 3 * c0 : 0;
    int a1 = h1 ? 3 * c1 : 0;

    // 12 independent loads in flight
    float4 pa0 = pred[a0 + 0], pb0 = pred[a0 + 1], pc0 = pred[a0 + 2];
    float4 ta0 = targ[a0 + 0], tb0 = targ[a0 + 1], tc0 = targ[a0 + 2];
    float4 pa1 = pred[a1 + 0], pb1 = pred[a1 + 1], pc1 = pred[a1 + 2];
    float4 ta1 = targ[a1 + 0], tb1 = targ[a1 + 1], tc1 = targ[a1 + 2];

    float l0 = 0.f, q0 = 0.f, n0 = 0.f, o0 = 0.f, s0 = 0.f;
    if (h0) cell_loss(pa0, pb0, pc0, ta0, tb0, tc0, l0, q0, n0, o0, s0);
    float l1 = 0.f, q1 = 0.f, n1 = 0.f, o1 = 0.f, s1 = 0.f;
    if (h1) cell_loss(pa1, pb1, pc1, ta1, tb1, tc1, l1, q1, n1, o1, s1);

    loc = l0 + l1; contain = q0 + q1; notcont = n0 + n1;
    nooobj = o0 + o1; cls = s0 + s1;

    // wave64 down-reduce
    #pragma unroll
    for (int off = 32; off > 0; off >>= 1) {
        loc     += __shfl_down(loc, off, 64);
        contain += __shfl_down(contain, off, 64);
        notcont += __shfl_down(notcont, off, 64);
        nooobj  += __shfl_down(nooobj, off, 64);
        cls     += __shfl_down(cls, off, 64);
    }

    __shared__ float sm[NTHREADS / 64][5];
    int wave = threadIdx.x >> 6;
    int lane = threadIdx.x & 63;
    if (lane == 0) {
        sm[wave][0] = loc; sm[wave][1] = contain; sm[wave][2] = notcont;
        sm[wave][3] = nooobj; sm[wave][4] = cls;
    }
    __syncthreads();
    if (threadIdx.x == 0) {
        float r0 = 0.f, r1 = 0.f, r2 = 0.f, r3 = 0.f, r4 = 0.f;
        #pragma unroll
        for (int w = 0; w < NTHREADS / 64; ++w) {
            r0 += sm[w][0]; r1 += sm[w][1]; r2 += sm[w][2];
            r3 += sm[w][3]; r4 += sm[w][4];
        }
        float* row = partial + (size_t)blockIdx.x * 8;   // 8-float padded slot
        row[0] = r0; row[1] = r1; row[2] = r2; row[3] = r3; row[4] = r4;
    }
}

// Stage 2: one block reduces the 2048 x 5 partials and applies scales.
__global__ __launch_bounds__(NTHREADS) void finalize_kernel(
    const float* __restrict__ partial, float* __restrict__ out)
{
    float s0 = 0.f, s1 = 0.f, s2 = 0.f, s3 = 0.f, s4 = 0.f;
    for (int b = threadIdx.x; b < NBLOCKS; b += NTHREADS) {
        const float* row = partial + (size_t)b * 8;
        s0 += row[0]; s1 += row[1]; s2 += row[2]; s3 += row[3]; s4 += row[4];
    }

    #pragma unroll
    for (int off = 32; off > 0; off >>= 1) {
        s0 += __shfl_down(s0, off, 64);
        s1 += __shfl_down(s1, off, 64);
        s2 += __shfl_down(s2, off, 64);
        s3 += __shfl_down(s3, off, 64);
        s4 += __shfl_down(s4, off, 64);
    }

    __shared__ float sm[NTHREADS / 64][5];
    int wave = threadIdx.x >> 6;
    int lane = threadIdx.x & 63;
    if (lane == 0) {
        sm[wave][0] = s0; sm[wave][1] = s1; sm[wave][2] = s2;
        sm[wave][3] = s3; sm[wave][4] = s4;
    }
    __syncthreads();
    if (threadIdx.x == 0) {
        float a0 = 0.f, a1 = 0.f, a2 = 0.f, a3 = 0.f, a4 = 0.f;
        #pragma unroll
        for (int w = 0; w < NTHREADS / 64; ++w) {
            a0 += sm[w][0]; a1 += sm[w][1]; a2 += sm[w][2];
            a3 += sm[w][3]; a4 += sm[w][4];
        }
        float part0 = 1.4f * a0;   // LOC_SCALE * loc
        float part1 = 4.0f * a1;   // CONTAIN_SCALE * contain
        float part2 = a2;          // not_contain
        float part3 = 1.2f * a3;   // L_NOOBJ * nooobj
        float part4 = 0.5f * a4;   // CLASS_SCALE * class
        out[0] = part0 + part1 + part2 + part3 + part4;
        out[1] = part0;
        out[2] = part1;
        out[3] = part2;
        out[4] = part3;
        out[5] = part4;
    }
}

extern "C" void kernel_launch(void* const* d_in, const int* in_sizes, int n_in,
                              void* d_out, int out_size, void* d_ws, size_t ws_size,
                              hipStream_t stream)
{
    const float4* pred = (const float4*)d_in[0];
    const float4* targ = (const float4*)d_in[1];
    float* partial = (float*)d_ws;     // NBLOCKS * 8 floats = 64 KB
    float* out = (float*)d_out;
    int ncells = in_sizes[0] / 12;     // 64*128*128 = 1,048,576

    yolo_loss_kernel<<<NBLOCKS, NTHREADS, 0, stream>>>(pred, targ, partial, ncells);
    finalize_kernel<<<1, NTHREADS, 0, stream>>>(partial, out);
}